// Round 9
// baseline (15597.560 us; speedup 1.0000x reference)
//
#include <hip/hip_runtime.h>
#include <stdint.h>

#define B_    32
#define S_    1024
#define HIN   1024
#define NBLK  64
#define DBLK  16
#define HOUT  1024
#define NGATE 1152   // 64 i + 64 o + 1024 g
#define NSLICE 32    // gate slices (32 Ug rows + 2 Ui + 2 Uo each)

typedef __attribute__((ext_vector_type(8))) __bf16 bf16x8;
typedef __attribute__((ext_vector_type(4))) float  f32x4;

__device__ __forceinline__ unsigned short f2bf(float f) {
    union { float f; unsigned u; } v; v.f = f;
    return (unsigned short)((v.u + 0x7fffu + ((v.u >> 16) & 1u)) >> 16);
}
__device__ __forceinline__ float bf2f(unsigned short h) {
    union { unsigned u; float f; } v; v.u = ((unsigned)h) << 16; return v.f;
}
// fp32 -> hi+lo bf16 (v ~= hi + lo, residual <= 2^-18 |v|)
__device__ __forceinline__ void split1(float f, unsigned short& hi, unsigned short& lo) {
    hi = f2bf(f);
    lo = f2bf(f - bf2f(hi));
}

// gate-row mapping for a slice: rows 0..31 = Ug[slice*32+r], 32..33 = Ui[2s..], 34..35 = Uo[2s..]
__device__ __forceinline__ int slice_row(int slice, int r) {
    return (r < 32) ? (128 + slice * 32 + r)
         : (r < 34) ? (slice * 2 + (r - 32))
                    : (64 + slice * 2 + (r - 34));
}

// ---------------- phase 0: split W,U into hi/lo bf16; split h0 into planes ----------------
__global__ void k_init(const float* __restrict__ Wi, const float* __restrict__ Wo,
                       const float* __restrict__ Wg,
                       const float* __restrict__ Ui, const float* __restrict__ Uo,
                       const float* __restrict__ Ug, const float* __restrict__ h0,
                       unsigned short* __restrict__ WsH, unsigned short* __restrict__ WsL,
                       unsigned short* __restrict__ UsH, unsigned short* __restrict__ UsL,
                       unsigned short* __restrict__ hbH, unsigned short* __restrict__ hbL)
{
    int idx = blockIdx.x * 256 + threadIdx.x;
    const int nW = NGATE * HOUT / 4;           // 294912 quads per matrix set
    float4 v; unsigned short *dH, *dL;
    if (idx < nW) {
        int f = idx * 4; int row = f >> 10, k = f & 1023;
        const float* src = (row < 64)  ? (Wi + (size_t)row * HIN)
                         : (row < 128) ? (Wo + (size_t)(row - 64) * HIN)
                                       : (Wg + (size_t)(row - 128) * HIN);
        v = *(const float4*)(src + k);
        dH = WsH + f; dL = WsL + f;
    } else if (idx < 2 * nW) {
        int f = (idx - nW) * 4; int row = f >> 10, k = f & 1023;
        const float* src = (row < 64)  ? (Ui + (size_t)row * HOUT)
                         : (row < 128) ? (Uo + (size_t)(row - 64) * HOUT)
                                       : (Ug + (size_t)(row - 128) * HOUT);
        v = *(const float4*)(src + k);
        dH = UsH + f; dL = UsL + f;
    } else {
        int f = (idx - 2 * nW) * 4;
        if (f >= B_ * HOUT) return;
        v = *(const float4*)(h0 + f);
        dH = hbH + f; dL = hbL + f;            // slot 0
    }
    unsigned short th[4], tl[4];
    split1(v.x, th[0], tl[0]); split1(v.y, th[1], tl[1]);
    split1(v.z, th[2], tl[2]); split1(v.w, th[3], tl[3]);
    *(uint2*)dH = *(const uint2*)th;
    *(uint2*)dL = *(const uint2*)tl;
}

// ---------------- phase 1: gate pre-projection GEMM (bf16x3) ----------------
#define BM 128
#define BN 128
#define BK 32
#define LDP 56

__global__ __launch_bounds__(256) void k_gates(
    const float* __restrict__ x,
    const unsigned short* __restrict__ WsH, const unsigned short* __restrict__ WsL,
    const float* __restrict__ bi, const float* __restrict__ bo, const float* __restrict__ bg,
    float* __restrict__ c_out, float* __restrict__ h_out)
{
    __shared__ unsigned short AlH[BM][LDP], AlL[BM][LDP];
    __shared__ unsigned short BlH[BN][LDP], BlL[BN][LDP];
    const int tid  = threadIdx.x;
    const int bm   = blockIdx.x, bn = blockIdx.y;
    const int wave = tid >> 6,  lane = tid & 63;
    const int l15  = lane & 15, l4 = lane >> 4;
    const int wm   = wave >> 1, wn = wave & 1;
    const int rbase = tid >> 3;          // 0..31
    const int c4    = (tid & 7) * 4;     // 0..28

    f32x4 acc[4][4] = {};

    for (int kk = 0; kk < HIN; kk += BK) {
        #pragma unroll
        for (int i = 0; i < 4; ++i) {
            int row = rbase + 32 * i;
            float4 v = *(const float4*)(x + (size_t)(bm * BM + row) * HIN + kk + c4);
            unsigned short th[4], tl[4];
            split1(v.x, th[0], tl[0]); split1(v.y, th[1], tl[1]);
            split1(v.z, th[2], tl[2]); split1(v.w, th[3], tl[3]);
            *(uint2*)&AlH[row][c4] = *(const uint2*)th;
            *(uint2*)&AlL[row][c4] = *(const uint2*)tl;
            int n = bn * BN + row;
            *(uint2*)&BlH[row][c4] = *(const uint2*)(WsH + (size_t)n * HIN + kk + c4);
            *(uint2*)&BlL[row][c4] = *(const uint2*)(WsL + (size_t)n * HIN + kk + c4);
        }
        __syncthreads();
        uint4 ah[4], al[4], bh4[4], bl4[4];
        #pragma unroll
        for (int mi = 0; mi < 4; ++mi) {
            ah[mi] = *(const uint4*)&AlH[wm * 64 + mi * 16 + l15][l4 * 8];
            al[mi] = *(const uint4*)&AlL[wm * 64 + mi * 16 + l15][l4 * 8];
        }
        #pragma unroll
        for (int ni = 0; ni < 4; ++ni) {
            bh4[ni] = *(const uint4*)&BlH[wn * 64 + ni * 16 + l15][l4 * 8];
            bl4[ni] = *(const uint4*)&BlL[wn * 64 + ni * 16 + l15][l4 * 8];
        }
        #pragma unroll
        for (int mi = 0; mi < 4; ++mi) {
            #pragma unroll
            for (int ni = 0; ni < 4; ++ni) {
                acc[mi][ni] = __builtin_amdgcn_mfma_f32_16x16x32_bf16(
                    __builtin_bit_cast(bf16x8, ah[mi]), __builtin_bit_cast(bf16x8, bh4[ni]),
                    acc[mi][ni], 0, 0, 0);
                acc[mi][ni] = __builtin_amdgcn_mfma_f32_16x16x32_bf16(
                    __builtin_bit_cast(bf16x8, ah[mi]), __builtin_bit_cast(bf16x8, bl4[ni]),
                    acc[mi][ni], 0, 0, 0);
                acc[mi][ni] = __builtin_amdgcn_mfma_f32_16x16x32_bf16(
                    __builtin_bit_cast(bf16x8, al[mi]), __builtin_bit_cast(bf16x8, bh4[ni]),
                    acc[mi][ni], 0, 0, 0);
            }
        }
        __syncthreads();
    }

    #pragma unroll
    for (int ni = 0; ni < 4; ++ni) {
        int n = bn * BN + wn * 64 + ni * 16 + l15;
        float bv = (n < 64) ? bi[n] : (n < 128) ? bo[n - 64] : bg[n - 128];
        #pragma unroll
        for (int mi = 0; mi < 4; ++mi) {
            #pragma unroll
            for (int r = 0; r < 4; ++r) {
                int m = bm * BM + wm * 64 + mi * 16 + l4 * 4 + r;
                float val = acc[mi][ni][r] + bv;
                if (n >= 128) {
                    h_out[(size_t)m * HOUT + (n - 128)] = val;
                } else if (n < 64) {
                    c_out[((size_t)m * NBLK + n) * DBLK + 0] = val;
                } else {
                    c_out[((size_t)m * NBLK + (n - 64)) * DBLK + 1] = val;
                }
            }
        }
    }
}

// ---------------- phase 2: persistent lockstep recurrence (bf16x3) ----------------
// 64 WGs x 256 thr (4 waves). slice = bid&31, group = bid>>5 (batches [16g,+16)).
// Waves 0-2 compute (wave = 16-gate-row group, FULL K), wave 3 = dedicated poller
// with s_sleep throttle (kills the R5-R8 poll-storm). A-fragments loaded directly
// from LLC with a manual 2-stage pipeline (4-ks batches, double-buffered regs).
// Whi in swizzled LDS; Wlo streamed from L2; h as bf16 hi/lo planes (R4 format).
__global__ __launch_bounds__(256, 1) void k_rec(
    const float* __restrict__ c0,
    float* __restrict__ c_out, float* __restrict__ h_out,
    const unsigned short* __restrict__ UsH, const unsigned short* __restrict__ UsL,
    unsigned short* __restrict__ hbH, unsigned short* __restrict__ hbL,
    unsigned int* __restrict__ flags)
{
    __shared__ unsigned short Whi[37][1024];   // 74 KB swizzled, row 36 = junk pad
    __shared__ float pre[16][52];              // 3.3 KB

    const int tid   = threadIdx.x;
    const int slice = blockIdx.x & 31;
    const int group = blockIdx.x >> 5;     // 0 or 1
    const int wave  = tid >> 6, lane = tid & 63;
    const int l15   = lane & 15, l4 = lane >> 4;

    // ---- stage U hi-plane into LDS, XOR-swizzled in 16B units: unit u -> u^(r&7)
    for (int idx = tid; idx < 36 * 128; idx += 256) {
        int r = idx >> 7, u = idx & 127;
        uint4 v = *(const uint4*)(UsH + (size_t)slice_row(slice, r) * HOUT + u * 8);
        *(uint4*)((char*)&Whi[0][0] + r * 2048 + ((u ^ (r & 7)) << 4)) = v;
    }

    // ---- compute-wave addressing (waves 0-2; wave 3 = poller)
    const int grow = wave * 16 + l15;            // 0..47 (valid < 36)
    const int wr   = (grow < 36) ? grow : 36;
    const int rowbyte = wr * 2048;
    const int rm      = wr & 7;
    const int srow = (grow < 36) ? slice_row(slice, grow) : 0;
    const unsigned short* wlp = UsL + (size_t)srow * HOUT + l4 * 8;

    // ---- per-thread epilogue mapping: 2 consecutive h-cols
    const int e0   = tid * 2;
    const int bl   = e0 >> 5;             // 0..15 batch-in-group
    const int col0 = e0 & 31;             // even
    const int Bg   = group * 16 + bl;
    const int hcol = slice * 32 + col0;
    const int blkI = hcol >> 4, d0 = hcol & 15;
    float cr0 = c0[((size_t)Bg * NBLK + blkI) * DBLK + d0];
    float cr1 = c0[((size_t)Bg * NBLK + blkI) * DBLK + d0 + 1];

    unsigned int* flagbase = flags + (size_t)group * NSLICE * 32;
    unsigned int* myflag   = flagbase + slice * 32;                   // 128B apart

    // prefetch step-0 gate preactivations (cold HBM; hidden before loop)
    size_t rowoff = (size_t)Bg * S_;
    float xg0 = h_out[rowoff * HOUT + hcol];
    float xg1 = h_out[rowoff * HOUT + hcol + 1];
    float xi  = c_out[(rowoff * NBLK + blkI) * DBLK + 0];
    float xo  = c_out[(rowoff * NBLK + blkI) * DBLK + 1];

    __syncthreads();   // Whi ready

    for (int t = 0; t < S_; ++t) {
        // ---- 1. single-wave throttled poll (wave 3), release via barrier
        if (wave == 3 && t > 0) {
            unsigned int* fl = flagbase + (lane & 31) * 32;
            for (;;) {
                unsigned v = __hip_atomic_load(fl, __ATOMIC_RELAXED, __HIP_MEMORY_SCOPE_AGENT);
                if (__all((int)(v >= (unsigned)t))) break;
                __builtin_amdgcn_s_sleep(1);
            }
        }
        __syncthreads();

        // ---- 2. compute waves: pipelined direct-LLC A loads + MFMA (full K)
        if (wave < 3) {
            const unsigned long long* aH = (const unsigned long long*)
                (hbH + ((size_t)(t & 1) * B_ + group * 16 + l15) * HOUT) + l4 * 2;
            const unsigned long long* aL = (const unsigned long long*)
                (hbL + ((size_t)(t & 1) * B_ + group * 16 + l15) * HOUT) + l4 * 2;

            f32x4 acc = {0.f, 0.f, 0.f, 0.f};
            uint4 ah0[4], al0[4], wv0[4], ah1[4], al1[4], wv1[4];

            #define LOADB(bb, AH, AL, WV)                                              \
                _Pragma("unroll")                                                       \
                for (int j = 0; j < 4; ++j) {                                           \
                    int ks = (bb) * 4 + j;                                              \
                    unsigned long long a0 = __hip_atomic_load(aH + ks * 8,              \
                        __ATOMIC_RELAXED, __HIP_MEMORY_SCOPE_AGENT);                    \
                    unsigned long long a1 = __hip_atomic_load(aH + ks * 8 + 1,          \
                        __ATOMIC_RELAXED, __HIP_MEMORY_SCOPE_AGENT);                    \
                    unsigned long long b0 = __hip_atomic_load(aL + ks * 8,              \
                        __ATOMIC_RELAXED, __HIP_MEMORY_SCOPE_AGENT);                    \
                    unsigned long long b1 = __hip_atomic_load(aL + ks * 8 + 1,          \
                        __ATOMIC_RELAXED, __HIP_MEMORY_SCOPE_AGENT);                    \
                    AH[j] = make_uint4((unsigned)a0, (unsigned)(a0 >> 32),              \
                                       (unsigned)a1, (unsigned)(a1 >> 32));             \
                    AL[j] = make_uint4((unsigned)b0, (unsigned)(b0 >> 32),              \
                                       (unsigned)b1, (unsigned)(b1 >> 32));             \
                    WV[j] = *(const uint4*)(wlp + ks * 32);                             \
                }

            #define COMPB(bb, AH, AL, WV)                                               \
                _Pragma("unroll")                                                       \
                for (int j = 0; j < 4; ++j) {                                           \
                    int ks = (bb) * 4 + j;                                              \
                    int u = ks * 4 + l4;                                                \
                    uint4 bh = *(const uint4*)((const char*)&Whi[0][0]                  \
                                   + rowbyte + ((u ^ rm) << 4));                        \
                    acc = __builtin_amdgcn_mfma_f32_16x16x32_bf16(                      \
                        __builtin_bit_cast(bf16x8, AH[j]), __builtin_bit_cast(bf16x8, bh), \
                        acc, 0, 0, 0);                                                  \
                    acc = __builtin_amdgcn_mfma_f32_16x16x32_bf16(                      \
                        __builtin_bit_cast(bf16x8, AL[j]), __builtin_bit_cast(bf16x8, bh), \
                        acc, 0, 0, 0);                                                  \
                    acc = __builtin_amdgcn_mfma_f32_16x16x32_bf16(                      \
                        __builtin_bit_cast(bf16x8, AH[j]), __builtin_bit_cast(bf16x8, WV[j]), \
                        acc, 0, 0, 0);                                                  \
                }

            LOADB(0, ah0, al0, wv0)
            #pragma unroll
            for (int b = 0; b < 8; ++b) {
                if (b & 1) {
                    if (b < 7) { LOADB(b + 1, ah0, al0, wv0) }
                    COMPB(b, ah1, al1, wv1)
                } else {
                    if (b < 7) { LOADB(b + 1, ah1, al1, wv1) }
                    COMPB(b, ah0, al0, wv0)
                }
            }
            #undef LOADB
            #undef COMPB

            #pragma unroll
            for (int r = 0; r < 4; ++r)
                pre[l4 * 4 + r][grow] = acc[r];
        }
        __syncthreads();   // [A] pre complete

        // ---- 3. epilogue (uses prefetched xg/xi/xo)
        float gp0 = pre[bl][col0]     + xg0;
        float gp1 = pre[bl][col0 + 1] + xg1;
        float ip  = pre[bl][32 + (col0 >> 4)] + xi;
        float op  = pre[bl][34 + (col0 >> 4)] + xo;
        float ig  = 1.f / (1.f + __expf(-ip));
        float og  = 1.f / (1.f + __expf(-op));
        cr0 += ig * tanhf(gp0);
        cr1 += ig * tanhf(gp1);
        float h0v = og * tanhf(cr0);
        float h1v = og * tanhf(cr1);

        // ---- 4. publish h (hi/lo bf16 planes, agent scope) -- the critical path
        unsigned short h0h, h0l, h1h, h1l;
        split1(h0v, h0h, h0l); split1(h1v, h1h, h1l);
        size_t dsto = ((size_t)((t + 1) & 1) * B_ + Bg) * HOUT + hcol;
        __hip_atomic_store((unsigned int*)(hbH + dsto),
                           (unsigned)h0h | ((unsigned)h1h << 16),
                           __ATOMIC_RELAXED, __HIP_MEMORY_SCOPE_AGENT);
        __hip_atomic_store((unsigned int*)(hbL + dsto),
                           (unsigned)h0l | ((unsigned)h1l << 16),
                           __ATOMIC_RELAXED, __HIP_MEMORY_SCOPE_AGENT);

        asm volatile("s_waitcnt vmcnt(0)" ::: "memory");
        __syncthreads();   // [B] all publishes acked
        if (tid == 0)
            __hip_atomic_store(myflag, (unsigned)(t + 1),
                               __ATOMIC_RELAXED, __HIP_MEMORY_SCOPE_AGENT);

        // ---- 5. outputs + next-step prefetch (off the critical path)
        c_out[(rowoff * NBLK + blkI) * DBLK + d0]     = cr0;
        c_out[(rowoff * NBLK + blkI) * DBLK + d0 + 1] = cr1;
        h_out[rowoff * HOUT + hcol]     = h0v;
        h_out[rowoff * HOUT + hcol + 1] = h1v;

        if (t + 1 < S_) {
            rowoff = (size_t)Bg * S_ + (t + 1);
            xg0 = h_out[rowoff * HOUT + hcol];
            xg1 = h_out[rowoff * HOUT + hcol + 1];
            xi  = c_out[(rowoff * NBLK + blkI) * DBLK + 0];
            xo  = c_out[(rowoff * NBLK + blkI) * DBLK + 1];
        }
    }
}

// ---------------- launch ----------------
extern "C" void kernel_launch(void* const* d_in, const int* in_sizes, int n_in,
                              void* d_out, int out_size, void* d_ws, size_t ws_size,
                              hipStream_t stream) {
    const float* x  = (const float*)d_in[0];
    const float* h0 = (const float*)d_in[1];
    const float* c0 = (const float*)d_in[2];
    const float* Wi = (const float*)d_in[3];
    const float* bi = (const float*)d_in[4];
    const float* Wo = (const float*)d_in[5];
    const float* bo = (const float*)d_in[6];
    const float* Wg = (const float*)d_in[7];
    const float* bg = (const float*)d_in[8];
    const float* Ui = (const float*)d_in[9];
    const float* Uo = (const float*)d_in[10];
    const float* Ug = (const float*)d_in[11];

    float* c_out = (float*)d_out;
    float* h_out = c_out + (size_t)B_ * S_ * NBLK * DBLK;

    unsigned short* WsH  = (unsigned short*)d_ws;                    // [1152][1024]
    unsigned short* WsL  = WsH + (size_t)NGATE * HOUT;
    unsigned short* UsH  = WsL + (size_t)NGATE * HOUT;
    unsigned short* UsL  = UsH + (size_t)NGATE * HOUT;
    unsigned short* hbH  = UsL + (size_t)NGATE * HOUT;               // [2][32][1024]
    unsigned short* hbL  = hbH + (size_t)2 * B_ * HOUT;
    unsigned int*   flags = (unsigned int*)(hbL + (size_t)2 * B_ * HOUT); // 64 x 128B

    hipMemsetAsync(flags, 0, 64 * 32 * sizeof(unsigned int), stream);
    k_init<<<2336, 256, 0, stream>>>(Wi, Wo, Wg, Ui, Uo, Ug, h0, WsH, WsL, UsH, UsL, hbH, hbL);
    k_gates<<<dim3((B_ * S_) / BM, NGATE / BN), 256, 0, stream>>>(
        x, WsH, WsL, bi, bo, bg, c_out, h_out);
    k_rec<<<64, 256, 0, stream>>>(c0, c_out, h_out, UsH, UsL, hbH, hbL, flags);
}

// Round 10
// 14684.135 us; speedup vs baseline: 1.0622x; 1.0622x over previous
//
#include <hip/hip_runtime.h>
#include <stdint.h>

#define B_    32
#define S_    1024
#define HIN   1024
#define NBLK  64
#define DBLK  16
#define HOUT  1024
#define NGATE 1152   // 64 i + 64 o + 1024 g
#define NSLICE 32    // gate slices (32 Ug rows + 2 Ui + 2 Uo each)

typedef __attribute__((ext_vector_type(8))) __bf16 bf16x8;
typedef __attribute__((ext_vector_type(4))) float  f32x4;

__device__ __forceinline__ unsigned short f2bf(float f) {
    union { float f; unsigned u; } v; v.f = f;
    return (unsigned short)((v.u + 0x7fffu + ((v.u >> 16) & 1u)) >> 16);
}
__device__ __forceinline__ float bf2f(unsigned short h) {
    union { unsigned u; float f; } v; v.u = ((unsigned)h) << 16; return v.f;
}
// fp32 -> hi+lo bf16 (v ~= hi + lo, residual <= 2^-18 |v|)
__device__ __forceinline__ void split1(float f, unsigned short& hi, unsigned short& lo) {
    hi = f2bf(f);
    lo = f2bf(f - bf2f(hi));
}

// gate-row mapping for a slice: rows 0..31 = Ug[slice*32+r], 32..33 = Ui[2s..], 34..35 = Uo[2s..]
__device__ __forceinline__ int slice_row(int slice, int r) {
    return (r < 32) ? (128 + slice * 32 + r)
         : (r < 34) ? (slice * 2 + (r - 32))
                    : (64 + slice * 2 + (r - 34));
}

// ---------------- phase 0: split W,U into hi/lo bf16; split h0 into planes ----------------
__global__ void k_init(const float* __restrict__ Wi, const float* __restrict__ Wo,
                       const float* __restrict__ Wg,
                       const float* __restrict__ Ui, const float* __restrict__ Uo,
                       const float* __restrict__ Ug, const float* __restrict__ h0,
                       unsigned short* __restrict__ WsH, unsigned short* __restrict__ WsL,
                       unsigned short* __restrict__ UsH, unsigned short* __restrict__ UsL,
                       unsigned short* __restrict__ hbH, unsigned short* __restrict__ hbL)
{
    int idx = blockIdx.x * 256 + threadIdx.x;
    const int nW = NGATE * HOUT / 4;           // 294912 quads per matrix set
    float4 v; unsigned short *dH, *dL;
    if (idx < nW) {
        int f = idx * 4; int row = f >> 10, k = f & 1023;
        const float* src = (row < 64)  ? (Wi + (size_t)row * HIN)
                         : (row < 128) ? (Wo + (size_t)(row - 64) * HIN)
                                       : (Wg + (size_t)(row - 128) * HIN);
        v = *(const float4*)(src + k);
        dH = WsH + f; dL = WsL + f;
    } else if (idx < 2 * nW) {
        int f = (idx - nW) * 4; int row = f >> 10, k = f & 1023;
        const float* src = (row < 64)  ? (Ui + (size_t)row * HOUT)
                         : (row < 128) ? (Uo + (size_t)(row - 64) * HOUT)
                                       : (Ug + (size_t)(row - 128) * HOUT);
        v = *(const float4*)(src + k);
        dH = UsH + f; dL = UsL + f;
    } else {
        int f = (idx - 2 * nW) * 4;
        if (f >= B_ * HOUT) return;
        v = *(const float4*)(h0 + f);
        dH = hbH + f; dL = hbL + f;            // slot 0
    }
    unsigned short th[4], tl[4];
    split1(v.x, th[0], tl[0]); split1(v.y, th[1], tl[1]);
    split1(v.z, th[2], tl[2]); split1(v.w, th[3], tl[3]);
    *(uint2*)dH = *(const uint2*)th;
    *(uint2*)dL = *(const uint2*)tl;
}

// ---------------- phase 1: gate pre-projection GEMM (bf16x3) ----------------
#define BM 128
#define BN 128
#define BK 32
#define LDP 56

__global__ __launch_bounds__(256) void k_gates(
    const float* __restrict__ x,
    const unsigned short* __restrict__ WsH, const unsigned short* __restrict__ WsL,
    const float* __restrict__ bi, const float* __restrict__ bo, const float* __restrict__ bg,
    float* __restrict__ c_out, float* __restrict__ h_out)
{
    __shared__ unsigned short AlH[BM][LDP], AlL[BM][LDP];
    __shared__ unsigned short BlH[BN][LDP], BlL[BN][LDP];
    const int tid  = threadIdx.x;
    const int bm   = blockIdx.x, bn = blockIdx.y;
    const int wave = tid >> 6,  lane = tid & 63;
    const int l15  = lane & 15, l4 = lane >> 4;
    const int wm   = wave >> 1, wn = wave & 1;
    const int rbase = tid >> 3;          // 0..31
    const int c4    = (tid & 7) * 4;     // 0..28

    f32x4 acc[4][4] = {};

    for (int kk = 0; kk < HIN; kk += BK) {
        #pragma unroll
        for (int i = 0; i < 4; ++i) {
            int row = rbase + 32 * i;
            float4 v = *(const float4*)(x + (size_t)(bm * BM + row) * HIN + kk + c4);
            unsigned short th[4], tl[4];
            split1(v.x, th[0], tl[0]); split1(v.y, th[1], tl[1]);
            split1(v.z, th[2], tl[2]); split1(v.w, th[3], tl[3]);
            *(uint2*)&AlH[row][c4] = *(const uint2*)th;
            *(uint2*)&AlL[row][c4] = *(const uint2*)tl;
            int n = bn * BN + row;
            *(uint2*)&BlH[row][c4] = *(const uint2*)(WsH + (size_t)n * HIN + kk + c4);
            *(uint2*)&BlL[row][c4] = *(const uint2*)(WsL + (size_t)n * HIN + kk + c4);
        }
        __syncthreads();
        uint4 ah[4], al[4], bh4[4], bl4[4];
        #pragma unroll
        for (int mi = 0; mi < 4; ++mi) {
            ah[mi] = *(const uint4*)&AlH[wm * 64 + mi * 16 + l15][l4 * 8];
            al[mi] = *(const uint4*)&AlL[wm * 64 + mi * 16 + l15][l4 * 8];
        }
        #pragma unroll
        for (int ni = 0; ni < 4; ++ni) {
            bh4[ni] = *(const uint4*)&BlH[wn * 64 + ni * 16 + l15][l4 * 8];
            bl4[ni] = *(const uint4*)&BlL[wn * 64 + ni * 16 + l15][l4 * 8];
        }
        #pragma unroll
        for (int mi = 0; mi < 4; ++mi) {
            #pragma unroll
            for (int ni = 0; ni < 4; ++ni) {
                acc[mi][ni] = __builtin_amdgcn_mfma_f32_16x16x32_bf16(
                    __builtin_bit_cast(bf16x8, ah[mi]), __builtin_bit_cast(bf16x8, bh4[ni]),
                    acc[mi][ni], 0, 0, 0);
                acc[mi][ni] = __builtin_amdgcn_mfma_f32_16x16x32_bf16(
                    __builtin_bit_cast(bf16x8, ah[mi]), __builtin_bit_cast(bf16x8, bl4[ni]),
                    acc[mi][ni], 0, 0, 0);
                acc[mi][ni] = __builtin_amdgcn_mfma_f32_16x16x32_bf16(
                    __builtin_bit_cast(bf16x8, al[mi]), __builtin_bit_cast(bf16x8, bh4[ni]),
                    acc[mi][ni], 0, 0, 0);
            }
        }
        __syncthreads();
    }

    #pragma unroll
    for (int ni = 0; ni < 4; ++ni) {
        int n = bn * BN + wn * 64 + ni * 16 + l15;
        float bv = (n < 64) ? bi[n] : (n < 128) ? bo[n - 64] : bg[n - 128];
        #pragma unroll
        for (int mi = 0; mi < 4; ++mi) {
            #pragma unroll
            for (int r = 0; r < 4; ++r) {
                int m = bm * BM + wm * 64 + mi * 16 + l4 * 4 + r;
                float val = acc[mi][ni][r] + bv;
                if (n >= 128) {
                    h_out[(size_t)m * HOUT + (n - 128)] = val;
                } else if (n < 64) {
                    c_out[((size_t)m * NBLK + n) * DBLK + 0] = val;
                } else {
                    c_out[((size_t)m * NBLK + (n - 64)) * DBLK + 1] = val;
                }
            }
        }
    }
}

// ---------------- phase 2: persistent lockstep recurrence (bf16x3) ----------------
// 32 WGs x 256 thr. WG = slice (0..31); handles BOTH batch-groups, interleaved:
// per t: [phase g=0][phase g=1]. Chain g's publish->peer-detect latency hides
// under chain g^1's compute. Each phase is exactly the R4-proven structure:
// wave-0 flag poll, bulk LDS staging of h (hi/lo planes), hi-weights in 128
// pinned VGPRs, lo-weights in LDS, publish->vmcnt->barrier->flag, outputs and
// next-step prefetch after the flag (off the critical path).
__global__ __launch_bounds__(256, 1) void k_rec(
    const float* __restrict__ c0,
    float* __restrict__ c_out, float* __restrict__ h_out,
    const unsigned short* __restrict__ UsH, const unsigned short* __restrict__ UsL,
    unsigned short* __restrict__ hbH, unsigned short* __restrict__ hbL,
    unsigned int* __restrict__ flags)
{
    __shared__ unsigned short Wlo[37][1032];   // 74.6 KB (row 36 = zeros)
    __shared__ unsigned short HaH[16][1032];   // 33 KB
    __shared__ unsigned short HaL[16][1032];   // 33 KB
    __shared__ float pre[16][48];              // 3 KB

    const int tid   = threadIdx.x;
    const int slice = blockIdx.x;          // 0..31
    const int wave  = tid >> 6, lane = tid & 63;
    const int l15   = lane & 15, l4 = lane >> 4;

    // fill Wlo (lo-plane weights) into LDS; row 36 zeroed
    for (int idx = tid; idx < 37 * 128; idx += 256) {
        int row = idx >> 7, c8 = idx & 127;
        uint4 v = make_uint4(0, 0, 0, 0);
        if (row < 36)
            v = *(const uint4*)(UsL + (size_t)slice_row(slice, row) * HOUT + c8 * 8);
        *(uint4*)&Wlo[row][c8 * 8] = v;
    }

    // pin hi-plane B-fragments in 128 VGPRs (waves 0-2 compute)
    const int grow  = wave * 16 + l15;
    const bool valid = (wave < 3) && (grow < 36);
    const int wrow  = valid ? grow : 36;       // LDS row for lo-plane (36 = zeros)
    uint4 bwh[32];
    {
        int srow = valid ? slice_row(slice, grow) : 0;
        const unsigned short* ph = UsH + (size_t)srow * HOUT + l4 * 8;
        #pragma unroll
        for (int ks = 0; ks < 32; ++ks)
            bwh[ks] = valid ? *(const uint4*)(ph + ks * 32) : make_uint4(0, 0, 0, 0);
    }

    // per-thread epilogue mapping: 2 consecutive h-cols, per group
    const int e0   = tid * 2;
    const int bl   = e0 >> 5;             // 0..15 batch-in-group
    const int col0 = e0 & 31;             // even
    const int hcol = slice * 32 + col0;
    const int blkI = hcol >> 4, d0 = hcol & 15;

    float cr0[2], cr1[2], xg0[2], xg1[2], xiv[2], xov[2];
    #pragma unroll
    for (int g = 0; g < 2; ++g) {
        int Bg = g * 16 + bl;
        cr0[g] = c0[((size_t)Bg * NBLK + blkI) * DBLK + d0];
        cr1[g] = c0[((size_t)Bg * NBLK + blkI) * DBLK + d0 + 1];
        size_t ro = (size_t)Bg * S_;      // t = 0
        xg0[g] = h_out[ro * HOUT + hcol];
        xg1[g] = h_out[ro * HOUT + hcol + 1];
        xiv[g] = c_out[(ro * NBLK + blkI) * DBLK + 0];
        xov[g] = c_out[(ro * NBLK + blkI) * DBLK + 1];
    }

    __syncthreads();   // Wlo ready

    for (int t = 0; t < S_; ++t) {
        #pragma unroll
        for (int g = 0; g < 2; ++g) {
            unsigned int* flagbase = flags + (size_t)g * NSLICE * 32;
            const int Bg = g * 16 + bl;

            // ---- 1. poll chain-g flags (wave 0 only; others wait at barrier)
            if (t > 0) {
                if (wave == 0) {
                    unsigned int* fl = flagbase + (lane & 31) * 32;
                    unsigned v;
                    do {
                        v = __hip_atomic_load(fl, __ATOMIC_RELAXED, __HIP_MEMORY_SCOPE_AGENT);
                    } while (!__all((int)(v >= (unsigned)t)));
                }
                __syncthreads();
            }

            // ---- 2. bulk-stage h_t (group g, slot t&1) hi/lo planes into LDS
            const unsigned long long* srcH =
                (const unsigned long long*)(hbH + ((size_t)(t & 1) * B_ + g * 16) * HOUT);
            const unsigned long long* srcL =
                (const unsigned long long*)(hbL + ((size_t)(t & 1) * B_ + g * 16) * HOUT);
            #pragma unroll
            for (int it = 0; it < 16; ++it) {
                int chunk = it * 256 + tid;           // 16 rows x 256 chunks
                int r = chunk >> 8, c8 = chunk & 255;
                unsigned long long vh = __hip_atomic_load(srcH + chunk,
                                            __ATOMIC_RELAXED, __HIP_MEMORY_SCOPE_AGENT);
                unsigned long long vl = __hip_atomic_load(srcL + chunk,
                                            __ATOMIC_RELAXED, __HIP_MEMORY_SCOPE_AGENT);
                *(unsigned long long*)&HaH[r][c8 * 4] = vh;
                *(unsigned long long*)&HaL[r][c8 * 4] = vl;
            }
            __syncthreads();

            // ---- 3. MFMA (waves 0-2): hi from VGPR, lo from LDS
            if (wave < 3) {
                f32x4 acc = {0.f, 0.f, 0.f, 0.f};
                #pragma unroll
                for (int ks = 0; ks < 32; ++ks) {
                    uint4 auh = *(const uint4*)&HaH[l15][ks * 32 + l4 * 8];
                    uint4 aul = *(const uint4*)&HaL[l15][ks * 32 + l4 * 8];
                    uint4 bl_ = *(const uint4*)&Wlo[wrow][ks * 32 + l4 * 8];
                    acc = __builtin_amdgcn_mfma_f32_16x16x32_bf16(
                            __builtin_bit_cast(bf16x8, auh), __builtin_bit_cast(bf16x8, bwh[ks]), acc, 0, 0, 0);
                    acc = __builtin_amdgcn_mfma_f32_16x16x32_bf16(
                            __builtin_bit_cast(bf16x8, aul), __builtin_bit_cast(bf16x8, bwh[ks]), acc, 0, 0, 0);
                    acc = __builtin_amdgcn_mfma_f32_16x16x32_bf16(
                            __builtin_bit_cast(bf16x8, auh), __builtin_bit_cast(bf16x8, bl_), acc, 0, 0, 0);
                }
                #pragma unroll
                for (int r = 0; r < 4; ++r)
                    pre[l4 * 4 + r][grow] = acc[r];
            }
            __syncthreads();

            // ---- 4. epilogue (prefetched xg/xi/xo) + state update
            float gp0 = pre[bl][col0]     + xg0[g];
            float gp1 = pre[bl][col0 + 1] + xg1[g];
            float ip  = pre[bl][32 + (col0 >> 4)] + xiv[g];
            float op  = pre[bl][34 + (col0 >> 4)] + xov[g];
            float ig  = 1.f / (1.f + __expf(-ip));
            float og  = 1.f / (1.f + __expf(-op));
            cr0[g] += ig * tanhf(gp0);
            cr1[g] += ig * tanhf(gp1);
            float h0v = og * tanhf(cr0[g]);
            float h1v = og * tanhf(cr1[g]);

            // ---- 5. publish h_{t+1} (hi/lo planes, agent scope) -- critical path
            unsigned short h0h, h0l, h1h, h1l;
            split1(h0v, h0h, h0l); split1(h1v, h1h, h1l);
            size_t dsto = ((size_t)((t + 1) & 1) * B_ + Bg) * HOUT + hcol;
            __hip_atomic_store((unsigned int*)(hbH + dsto),
                               (unsigned)h0h | ((unsigned)h1h << 16),
                               __ATOMIC_RELAXED, __HIP_MEMORY_SCOPE_AGENT);
            __hip_atomic_store((unsigned int*)(hbL + dsto),
                               (unsigned)h0l | ((unsigned)h1l << 16),
                               __ATOMIC_RELAXED, __HIP_MEMORY_SCOPE_AGENT);

            asm volatile("s_waitcnt vmcnt(0)" ::: "memory");
            __syncthreads();   // all publishes acked
            if (tid == 0)
                __hip_atomic_store(flagbase + slice * 32, (unsigned)(t + 1),
                                   __ATOMIC_RELAXED, __HIP_MEMORY_SCOPE_AGENT);

            // ---- 6. outputs + next-step prefetch (off the critical path;
            //         latency hides under the other chain's phase)
            size_t ro = (size_t)Bg * S_ + t;
            c_out[(ro * NBLK + blkI) * DBLK + d0]     = cr0[g];
            c_out[(ro * NBLK + blkI) * DBLK + d0 + 1] = cr1[g];
            h_out[ro * HOUT + hcol]     = h0v;
            h_out[ro * HOUT + hcol + 1] = h1v;

            if (t + 1 < S_) {
                size_t rn = (size_t)Bg * S_ + (t + 1);
                xg0[g] = h_out[rn * HOUT + hcol];
                xg1[g] = h_out[rn * HOUT + hcol + 1];
                xiv[g] = c_out[(rn * NBLK + blkI) * DBLK + 0];
                xov[g] = c_out[(rn * NBLK + blkI) * DBLK + 1];
            }
        }
    }
}

// ---------------- launch ----------------
extern "C" void kernel_launch(void* const* d_in, const int* in_sizes, int n_in,
                              void* d_out, int out_size, void* d_ws, size_t ws_size,
                              hipStream_t stream) {
    const float* x  = (const float*)d_in[0];
    const float* h0 = (const float*)d_in[1];
    const float* c0 = (const float*)d_in[2];
    const float* Wi = (const float*)d_in[3];
    const float* bi = (const float*)d_in[4];
    const float* Wo = (const float*)d_in[5];
    const float* bo = (const float*)d_in[6];
    const float* Wg = (const float*)d_in[7];
    const float* bg = (const float*)d_in[8];
    const float* Ui = (const float*)d_in[9];
    const float* Uo = (const float*)d_in[10];
    const float* Ug = (const float*)d_in[11];

    float* c_out = (float*)d_out;
    float* h_out = c_out + (size_t)B_ * S_ * NBLK * DBLK;

    unsigned short* WsH  = (unsigned short*)d_ws;                    // [1152][1024]
    unsigned short* WsL  = WsH + (size_t)NGATE * HOUT;
    unsigned short* UsH  = WsL + (size_t)NGATE * HOUT;
    unsigned short* UsL  = UsH + (size_t)NGATE * HOUT;
    unsigned short* hbH  = UsL + (size_t)NGATE * HOUT;               // [2][32][1024]
    unsigned short* hbL  = hbH + (size_t)2 * B_ * HOUT;
    unsigned int*   flags = (unsigned int*)(hbL + (size_t)2 * B_ * HOUT); // [2][32]x128B

    hipMemsetAsync(flags, 0, 64 * 32 * sizeof(unsigned int), stream);
    k_init<<<2336, 256, 0, stream>>>(Wi, Wo, Wg, Ui, Uo, Ug, h0, WsH, WsL, UsH, UsL, hbH, hbL);
    k_gates<<<dim3((B_ * S_) / BM, NGATE / BN), 256, 0, stream>>>(
        x, WsH, WsL, bi, bo, bg, c_out, h_out);
    k_rec<<<32, 256, 0, stream>>>(c0, c_out, h_out, UsH, UsL, hbH, hbL, flags);
}

// Round 11
// 5428.222 us; speedup vs baseline: 2.8734x; 2.7051x over previous
//
#include <hip/hip_runtime.h>
#include <stdint.h>

#define B_    32
#define S_    1024
#define HIN   1024
#define NBLK  64
#define DBLK  16
#define HOUT  1024
#define NGATE 1152   // 64 i + 64 o + 1024 g
#define NSLICE 32    // gate slices (32 Ug rows + 2 Ui + 2 Uo each)

typedef __attribute__((ext_vector_type(8))) __bf16 bf16x8;
typedef __attribute__((ext_vector_type(4))) float  f32x4;

__device__ __forceinline__ unsigned short f2bf(float f) {
    union { float f; unsigned u; } v; v.f = f;
    return (unsigned short)((v.u + 0x7fffu + ((v.u >> 16) & 1u)) >> 16);
}
__device__ __forceinline__ float bf2f(unsigned short h) {
    union { unsigned u; float f; } v; v.u = ((unsigned)h) << 16; return v.f;
}
// fp32 -> hi+lo bf16 (v ~= hi + lo, residual <= 2^-18 |v|)
__device__ __forceinline__ void split1(float f, unsigned short& hi, unsigned short& lo) {
    hi = f2bf(f);
    lo = f2bf(f - bf2f(hi));
}

// gate-row mapping for a slice: rows 0..31 = Ug[slice*32+r], 32..33 = Ui[2s..], 34..35 = Uo[2s..]
__device__ __forceinline__ int slice_row(int slice, int r) {
    return (r < 32) ? (128 + slice * 32 + r)
         : (r < 34) ? (slice * 2 + (r - 32))
                    : (64 + slice * 2 + (r - 34));
}

// ---------------- phase 0: split W,U into hi/lo bf16; split h0 into planes ----------------
__global__ void k_init(const float* __restrict__ Wi, const float* __restrict__ Wo,
                       const float* __restrict__ Wg,
                       const float* __restrict__ Ui, const float* __restrict__ Uo,
                       const float* __restrict__ Ug, const float* __restrict__ h0,
                       unsigned short* __restrict__ WsH, unsigned short* __restrict__ WsL,
                       unsigned short* __restrict__ UsH, unsigned short* __restrict__ UsL,
                       unsigned short* __restrict__ hbH, unsigned short* __restrict__ hbL)
{
    int idx = blockIdx.x * 256 + threadIdx.x;
    const int nW = NGATE * HOUT / 4;           // 294912 quads per matrix set
    float4 v; unsigned short *dH, *dL;
    if (idx < nW) {
        int f = idx * 4; int row = f >> 10, k = f & 1023;
        const float* src = (row < 64)  ? (Wi + (size_t)row * HIN)
                         : (row < 128) ? (Wo + (size_t)(row - 64) * HIN)
                                       : (Wg + (size_t)(row - 128) * HIN);
        v = *(const float4*)(src + k);
        dH = WsH + f; dL = WsL + f;
    } else if (idx < 2 * nW) {
        int f = (idx - nW) * 4; int row = f >> 10, k = f & 1023;
        const float* src = (row < 64)  ? (Ui + (size_t)row * HOUT)
                         : (row < 128) ? (Uo + (size_t)(row - 64) * HOUT)
                                       : (Ug + (size_t)(row - 128) * HOUT);
        v = *(const float4*)(src + k);
        dH = UsH + f; dL = UsL + f;
    } else {
        int f = (idx - 2 * nW) * 4;
        if (f >= B_ * HOUT) return;
        v = *(const float4*)(h0 + f);
        dH = hbH + f; dL = hbL + f;            // slot 0
    }
    unsigned short th[4], tl[4];
    split1(v.x, th[0], tl[0]); split1(v.y, th[1], tl[1]);
    split1(v.z, th[2], tl[2]); split1(v.w, th[3], tl[3]);
    *(uint2*)dH = *(const uint2*)th;
    *(uint2*)dL = *(const uint2*)tl;
}

// ---------------- phase 1: gate pre-projection GEMM (bf16x3) ----------------
#define BM 128
#define BN 128
#define BK 32
#define LDP 56

__global__ __launch_bounds__(256) void k_gates(
    const float* __restrict__ x,
    const unsigned short* __restrict__ WsH, const unsigned short* __restrict__ WsL,
    const float* __restrict__ bi, const float* __restrict__ bo, const float* __restrict__ bg,
    float* __restrict__ c_out, float* __restrict__ h_out)
{
    __shared__ unsigned short AlH[BM][LDP], AlL[BM][LDP];
    __shared__ unsigned short BlH[BN][LDP], BlL[BN][LDP];
    const int tid  = threadIdx.x;
    const int bm   = blockIdx.x, bn = blockIdx.y;
    const int wave = tid >> 6,  lane = tid & 63;
    const int l15  = lane & 15, l4 = lane >> 4;
    const int wm   = wave >> 1, wn = wave & 1;
    const int rbase = tid >> 3;          // 0..31
    const int c4    = (tid & 7) * 4;     // 0..28

    f32x4 acc[4][4] = {};

    for (int kk = 0; kk < HIN; kk += BK) {
        #pragma unroll
        for (int i = 0; i < 4; ++i) {
            int row = rbase + 32 * i;
            float4 v = *(const float4*)(x + (size_t)(bm * BM + row) * HIN + kk + c4);
            unsigned short th[4], tl[4];
            split1(v.x, th[0], tl[0]); split1(v.y, th[1], tl[1]);
            split1(v.z, th[2], tl[2]); split1(v.w, th[3], tl[3]);
            *(uint2*)&AlH[row][c4] = *(const uint2*)th;
            *(uint2*)&AlL[row][c4] = *(const uint2*)tl;
            int n = bn * BN + row;
            *(uint2*)&BlH[row][c4] = *(const uint2*)(WsH + (size_t)n * HIN + kk + c4);
            *(uint2*)&BlL[row][c4] = *(const uint2*)(WsL + (size_t)n * HIN + kk + c4);
        }
        __syncthreads();
        uint4 ah[4], al[4], bh4[4], bl4[4];
        #pragma unroll
        for (int mi = 0; mi < 4; ++mi) {
            ah[mi] = *(const uint4*)&AlH[wm * 64 + mi * 16 + l15][l4 * 8];
            al[mi] = *(const uint4*)&AlL[wm * 64 + mi * 16 + l15][l4 * 8];
        }
        #pragma unroll
        for (int ni = 0; ni < 4; ++ni) {
            bh4[ni] = *(const uint4*)&BlH[wn * 64 + ni * 16 + l15][l4 * 8];
            bl4[ni] = *(const uint4*)&BlL[wn * 64 + ni * 16 + l15][l4 * 8];
        }
        #pragma unroll
        for (int mi = 0; mi < 4; ++mi) {
            #pragma unroll
            for (int ni = 0; ni < 4; ++ni) {
                acc[mi][ni] = __builtin_amdgcn_mfma_f32_16x16x32_bf16(
                    __builtin_bit_cast(bf16x8, ah[mi]), __builtin_bit_cast(bf16x8, bh4[ni]),
                    acc[mi][ni], 0, 0, 0);
                acc[mi][ni] = __builtin_amdgcn_mfma_f32_16x16x32_bf16(
                    __builtin_bit_cast(bf16x8, ah[mi]), __builtin_bit_cast(bf16x8, bl4[ni]),
                    acc[mi][ni], 0, 0, 0);
                acc[mi][ni] = __builtin_amdgcn_mfma_f32_16x16x32_bf16(
                    __builtin_bit_cast(bf16x8, al[mi]), __builtin_bit_cast(bf16x8, bh4[ni]),
                    acc[mi][ni], 0, 0, 0);
            }
        }
        __syncthreads();
    }

    #pragma unroll
    for (int ni = 0; ni < 4; ++ni) {
        int n = bn * BN + wn * 64 + ni * 16 + l15;
        float bv = (n < 64) ? bi[n] : (n < 128) ? bo[n - 64] : bg[n - 128];
        #pragma unroll
        for (int mi = 0; mi < 4; ++mi) {
            #pragma unroll
            for (int r = 0; r < 4; ++r) {
                int m = bm * BM + wm * 64 + mi * 16 + l4 * 4 + r;
                float val = acc[mi][ni][r] + bv;
                if (n >= 128) {
                    h_out[(size_t)m * HOUT + (n - 128)] = val;
                } else if (n < 64) {
                    c_out[((size_t)m * NBLK + n) * DBLK + 0] = val;
                } else {
                    c_out[((size_t)m * NBLK + (n - 64)) * DBLK + 1] = val;
                }
            }
        }
    }
}

// ---------------- phase 2: persistent lockstep recurrence (bf16x3) ----------------
// 64 WGs x 256 thr (R4 skeleton). slice = bid&31, group = bid>>5 (batches [16g,+16)).
// ONE change vs the 7.58ms R4 kernel: h-staging uses inline-asm coherent loads
// (global_load_dwordx2 sc0 sc1) -- 32 loads in flight, ONE vmcnt drain -- instead
// of __hip_atomic_load, which LLVM refuses to reorder and therefore serialized
// into 16 back-to-back LLC round trips (~4.7us/step, the R4..R10 invariant cost).
__global__ __launch_bounds__(256, 1) void k_rec(
    const float* __restrict__ c0,
    float* __restrict__ c_out, float* __restrict__ h_out,
    const unsigned short* __restrict__ UsH, const unsigned short* __restrict__ UsL,
    unsigned short* __restrict__ hbH, unsigned short* __restrict__ hbL,
    unsigned int* __restrict__ flags)
{
    __shared__ unsigned short Wlo[37][1032];   // 74.6 KB (row 36 = zeros)
    __shared__ unsigned short HaH[16][1032];   // 33 KB
    __shared__ unsigned short HaL[16][1032];   // 33 KB
    __shared__ float pre[16][48];              // 3 KB

    const int tid   = threadIdx.x;
    const int slice = blockIdx.x & 31;
    const int group = blockIdx.x >> 5;     // 0 or 1
    const int wave  = tid >> 6, lane = tid & 63;
    const int l15   = lane & 15, l4 = lane >> 4;

    // fill Wlo (lo-plane weights) into LDS; row 36 zeroed
    for (int idx = tid; idx < 37 * 128; idx += 256) {
        int row = idx >> 7, c8 = idx & 127;
        uint4 v = make_uint4(0, 0, 0, 0);
        if (row < 36)
            v = *(const uint4*)(UsL + (size_t)slice_row(slice, row) * HOUT + c8 * 8);
        *(uint4*)&Wlo[row][c8 * 8] = v;
    }

    // hi-plane B-fragments (compiler may stream these from L2 each step; measured OK)
    const int grow  = wave * 16 + l15;
    const bool valid = (wave < 3) && (grow < 36);
    const int wrow  = valid ? grow : 36;       // LDS row for lo-plane (36 = zeros)
    uint4 bwh[32];
    {
        int srow = valid ? slice_row(slice, grow) : 0;
        const unsigned short* ph = UsH + (size_t)srow * HOUT + l4 * 8;
        #pragma unroll
        for (int ks = 0; ks < 32; ++ks)
            bwh[ks] = valid ? *(const uint4*)(ph + ks * 32) : make_uint4(0, 0, 0, 0);
    }

    // per-thread epilogue mapping: 2 consecutive h-cols
    const int e0   = tid * 2;
    const int bl   = e0 >> 5;             // 0..15 batch-in-group
    const int col0 = e0 & 31;             // even
    const int Bg   = group * 16 + bl;
    const int hcol = slice * 32 + col0;
    const int blkI = hcol >> 4, d0 = hcol & 15;
    float cr0 = c0[((size_t)Bg * NBLK + blkI) * DBLK + d0];
    float cr1 = c0[((size_t)Bg * NBLK + blkI) * DBLK + d0 + 1];

    unsigned int* flagbase = flags + (size_t)group * NSLICE * 32;
    unsigned int* myflag   = flagbase + slice * 32;                   // 128B apart
    unsigned int* pollfl   = flagbase + (lane & 31) * 32;

    // step-0 gate preactivation prefetch
    size_t rowoff = (size_t)Bg * S_;
    float xg0 = h_out[rowoff * HOUT + hcol];
    float xg1 = h_out[rowoff * HOUT + hcol + 1];
    float xi  = c_out[(rowoff * NBLK + blkI) * DBLK + 0];
    float xo  = c_out[(rowoff * NBLK + blkI) * DBLK + 1];

    __syncthreads();   // Wlo ready

    for (int t = 0; t < S_; ++t) {
        // ---- 1. poll (wave 0 only; lanes 0..31 watch the 32 producer slices)
        if (t > 0) {
            if (wave == 0) {
                unsigned v;
                do {
                    v = __hip_atomic_load(pollfl, __ATOMIC_RELAXED, __HIP_MEMORY_SCOPE_AGENT);
                } while (!__all((int)(v >= (unsigned)t)));
            }
            __syncthreads();
        }

        // ---- 2. bulk-stage h_t hi/lo planes: 32 coherent loads in flight, one drain.
        //         chunk(it) = plane_base + tid*8 + it*2048; LDS row it, col tid*4.
        {
            const char* bH = (const char*)(hbH + ((size_t)(t & 1) * B_ + group * 16) * HOUT) + tid * 8;
            const char* bL = (const char*)(hbL + ((size_t)(t & 1) * B_ + group * 16) * HOUT) + tid * 8;
            unsigned long long vh[16], vl[16];
            asm volatile(
                "global_load_dwordx2 %0, %16, off sc0 sc1\n\t"
                "global_load_dwordx2 %1, %16, off offset:2048 sc0 sc1\n\t"
                "global_load_dwordx2 %2, %17, off sc0 sc1\n\t"
                "global_load_dwordx2 %3, %17, off offset:2048 sc0 sc1\n\t"
                "global_load_dwordx2 %4, %18, off sc0 sc1\n\t"
                "global_load_dwordx2 %5, %18, off offset:2048 sc0 sc1\n\t"
                "global_load_dwordx2 %6, %19, off sc0 sc1\n\t"
                "global_load_dwordx2 %7, %19, off offset:2048 sc0 sc1\n\t"
                "global_load_dwordx2 %8, %20, off sc0 sc1\n\t"
                "global_load_dwordx2 %9, %20, off offset:2048 sc0 sc1\n\t"
                "global_load_dwordx2 %10, %21, off sc0 sc1\n\t"
                "global_load_dwordx2 %11, %21, off offset:2048 sc0 sc1\n\t"
                "global_load_dwordx2 %12, %22, off sc0 sc1\n\t"
                "global_load_dwordx2 %13, %22, off offset:2048 sc0 sc1\n\t"
                "global_load_dwordx2 %14, %23, off sc0 sc1\n\t"
                "global_load_dwordx2 %15, %23, off offset:2048 sc0 sc1\n\t"
                : "=&v"(vh[0]), "=&v"(vh[1]), "=&v"(vh[2]), "=&v"(vh[3]),
                  "=&v"(vh[4]), "=&v"(vh[5]), "=&v"(vh[6]), "=&v"(vh[7]),
                  "=&v"(vh[8]), "=&v"(vh[9]), "=&v"(vh[10]), "=&v"(vh[11]),
                  "=&v"(vh[12]), "=&v"(vh[13]), "=&v"(vh[14]), "=&v"(vh[15])
                : "v"(bH), "v"(bH + 4096), "v"(bH + 8192), "v"(bH + 12288),
                  "v"(bH + 16384), "v"(bH + 20480), "v"(bH + 24576), "v"(bH + 28672)
                : "memory");
            asm volatile(
                "global_load_dwordx2 %0, %16, off sc0 sc1\n\t"
                "global_load_dwordx2 %1, %16, off offset:2048 sc0 sc1\n\t"
                "global_load_dwordx2 %2, %17, off sc0 sc1\n\t"
                "global_load_dwordx2 %3, %17, off offset:2048 sc0 sc1\n\t"
                "global_load_dwordx2 %4, %18, off sc0 sc1\n\t"
                "global_load_dwordx2 %5, %18, off offset:2048 sc0 sc1\n\t"
                "global_load_dwordx2 %6, %19, off sc0 sc1\n\t"
                "global_load_dwordx2 %7, %19, off offset:2048 sc0 sc1\n\t"
                "global_load_dwordx2 %8, %20, off sc0 sc1\n\t"
                "global_load_dwordx2 %9, %20, off offset:2048 sc0 sc1\n\t"
                "global_load_dwordx2 %10, %21, off sc0 sc1\n\t"
                "global_load_dwordx2 %11, %21, off offset:2048 sc0 sc1\n\t"
                "global_load_dwordx2 %12, %22, off sc0 sc1\n\t"
                "global_load_dwordx2 %13, %22, off offset:2048 sc0 sc1\n\t"
                "global_load_dwordx2 %14, %23, off sc0 sc1\n\t"
                "global_load_dwordx2 %15, %23, off offset:2048 sc0 sc1\n\t"
                "s_waitcnt vmcnt(0)\n\t"
                : "=&v"(vl[0]), "=&v"(vl[1]), "=&v"(vl[2]), "=&v"(vl[3]),
                  "=&v"(vl[4]), "=&v"(vl[5]), "=&v"(vl[6]), "=&v"(vl[7]),
                  "=&v"(vl[8]), "=&v"(vl[9]), "=&v"(vl[10]), "=&v"(vl[11]),
                  "=&v"(vl[12]), "=&v"(vl[13]), "=&v"(vl[14]), "=&v"(vl[15])
                : "v"(bL), "v"(bL + 4096), "v"(bL + 8192), "v"(bL + 12288),
                  "v"(bL + 16384), "v"(bL + 20480), "v"(bL + 24576), "v"(bL + 28672)
                : "memory");
            #pragma unroll
            for (int it = 0; it < 16; ++it) {
                *(unsigned long long*)&HaH[it][tid * 4] = vh[it];
                *(unsigned long long*)&HaL[it][tid * 4] = vl[it];
            }
        }
        __syncthreads();

        // ---- 3. MFMA (waves 0-2): hi from bwh, lo from LDS
        if (wave < 3) {
            f32x4 acc = {0.f, 0.f, 0.f, 0.f};
            #pragma unroll
            for (int ks = 0; ks < 32; ++ks) {
                uint4 auh = *(const uint4*)&HaH[l15][ks * 32 + l4 * 8];
                uint4 aul = *(const uint4*)&HaL[l15][ks * 32 + l4 * 8];
                uint4 bl_ = *(const uint4*)&Wlo[wrow][ks * 32 + l4 * 8];
                acc = __builtin_amdgcn_mfma_f32_16x16x32_bf16(
                        __builtin_bit_cast(bf16x8, auh), __builtin_bit_cast(bf16x8, bwh[ks]), acc, 0, 0, 0);
                acc = __builtin_amdgcn_mfma_f32_16x16x32_bf16(
                        __builtin_bit_cast(bf16x8, aul), __builtin_bit_cast(bf16x8, bwh[ks]), acc, 0, 0, 0);
                acc = __builtin_amdgcn_mfma_f32_16x16x32_bf16(
                        __builtin_bit_cast(bf16x8, auh), __builtin_bit_cast(bf16x8, bl_), acc, 0, 0, 0);
            }
            #pragma unroll
            for (int r = 0; r < 4; ++r)
                pre[l4 * 4 + r][grow] = acc[r];
        }
        __syncthreads();

        // ---- 4. epilogue (prefetched xg/xi/xo) + state update
        float gp0 = pre[bl][col0]     + xg0;
        float gp1 = pre[bl][col0 + 1] + xg1;
        float ip  = pre[bl][32 + (col0 >> 4)] + xi;
        float op  = pre[bl][34 + (col0 >> 4)] + xo;
        float ig  = 1.f / (1.f + __expf(-ip));
        float og  = 1.f / (1.f + __expf(-op));
        cr0 += ig * tanhf(gp0);
        cr1 += ig * tanhf(gp1);
        float h0v = og * tanhf(cr0);
        float h1v = og * tanhf(cr1);

        // ---- 5. publish h_{t+1} (hi/lo planes, agent scope) -- critical path
        unsigned short h0h, h0l, h1h, h1l;
        split1(h0v, h0h, h0l); split1(h1v, h1h, h1l);
        size_t dsto = ((size_t)((t + 1) & 1) * B_ + Bg) * HOUT + hcol;
        __hip_atomic_store((unsigned int*)(hbH + dsto),
                           (unsigned)h0h | ((unsigned)h1h << 16),
                           __ATOMIC_RELAXED, __HIP_MEMORY_SCOPE_AGENT);
        __hip_atomic_store((unsigned int*)(hbL + dsto),
                           (unsigned)h0l | ((unsigned)h1l << 16),
                           __ATOMIC_RELAXED, __HIP_MEMORY_SCOPE_AGENT);

        asm volatile("s_waitcnt vmcnt(0)" ::: "memory");
        __syncthreads();   // all publishes acked
        if (tid == 0)
            __hip_atomic_store(myflag, (unsigned)(t + 1),
                               __ATOMIC_RELAXED, __HIP_MEMORY_SCOPE_AGENT);

        // ---- 6. outputs + next-step prefetch (off the critical path)
        size_t ro = (size_t)Bg * S_ + t;
        c_out[(ro * NBLK + blkI) * DBLK + d0]     = cr0;
        c_out[(ro * NBLK + blkI) * DBLK + d0 + 1] = cr1;
        h_out[ro * HOUT + hcol]     = h0v;
        h_out[ro * HOUT + hcol + 1] = h1v;

        if (t + 1 < S_) {
            size_t rn = (size_t)Bg * S_ + (t + 1);
            xg0 = h_out[rn * HOUT + hcol];
            xg1 = h_out[rn * HOUT + hcol + 1];
            xi  = c_out[(rn * NBLK + blkI) * DBLK + 0];
            xo  = c_out[(rn * NBLK + blkI) * DBLK + 1];
        }
    }
}

// ---------------- launch ----------------
extern "C" void kernel_launch(void* const* d_in, const int* in_sizes, int n_in,
                              void* d_out, int out_size, void* d_ws, size_t ws_size,
                              hipStream_t stream) {
    const float* x  = (const float*)d_in[0];
    const float* h0 = (const float*)d_in[1];
    const float* c0 = (const float*)d_in[2];
    const float* Wi = (const float*)d_in[3];
    const float* bi = (const float*)d_in[4];
    const float* Wo = (const float*)d_in[5];
    const float* bo = (const float*)d_in[6];
    const float* Wg = (const float*)d_in[7];
    const float* bg = (const float*)d_in[8];
    const float* Ui = (const float*)d_in[9];
    const float* Uo = (const float*)d_in[10];
    const float* Ug = (const float*)d_in[11];

    float* c_out = (float*)d_out;
    float* h_out = c_out + (size_t)B_ * S_ * NBLK * DBLK;

    unsigned short* WsH  = (unsigned short*)d_ws;                    // [1152][1024]
    unsigned short* WsL  = WsH + (size_t)NGATE * HOUT;
    unsigned short* UsH  = WsL + (size_t)NGATE * HOUT;
    unsigned short* UsL  = UsH + (size_t)NGATE * HOUT;
    unsigned short* hbH  = UsL + (size_t)NGATE * HOUT;               // [2][32][1024]
    unsigned short* hbL  = hbH + (size_t)2 * B_ * HOUT;
    unsigned int*   flags = (unsigned int*)(hbL + (size_t)2 * B_ * HOUT); // [2][32]x128B

    hipMemsetAsync(flags, 0, 64 * 32 * sizeof(unsigned int), stream);
    k_init<<<2336, 256, 0, stream>>>(Wi, Wo, Wg, Ui, Uo, Ug, h0, WsH, WsL, UsH, UsL, hbH, hbL);
    k_gates<<<dim3((B_ * S_) / BM, NGATE / BN), 256, 0, stream>>>(
        x, WsH, WsL, bi, bo, bg, c_out, h_out);
    k_rec<<<64, 256, 0, stream>>>(c0, c_out, h_out, UsH, UsL, hbH, hbL, flags);
}